// Round 3
// baseline (511.056 us; speedup 1.0000x reference)
//
#include <hip/hip_runtime.h>
#include <hip/hip_bf16.h>
#include <cstdint>

#define B_ 256
#define P_ 196
#define D_ 512
#define A_ 512

#define OUT_CHAT  0
#define OUT_ALPHA (B_*D_)            // 131072
#define OUT_BETA  (B_*D_ + B_*P_)    // 181248

typedef unsigned short ushort_t;
typedef uint32_t u32;
typedef uint64_t u64;
typedef __attribute__((ext_vector_type(8))) __bf16 bf16x8;
typedef __attribute__((ext_vector_type(4))) float f32x4;

__device__ __forceinline__ ushort_t f2bf(float f) {
    union { float f; u32 i; } v; v.f = f;
    u32 r = (v.i + 0x7fffu + ((v.i >> 16) & 1u)) >> 16;
    return (ushort_t)r;
}
__device__ __forceinline__ u64 pack4bf(float4 v) {
    return (u64)f2bf(v.x) | ((u64)f2bf(v.y) << 16)
         | ((u64)f2bf(v.z) << 32) | ((u64)f2bf(v.w) << 48);
}
// tanh(x) = 1 - 2/(1+e^{2x}); exact at +-inf limits, ~1e-6 abs err
__device__ __forceinline__ float tanh_fast(float x) {
    float e = __expf(2.0f * x);
    return 1.0f - 2.0f / (e + 1.0f);
}

// ---------------- K0: WvT[a][d] = bf16(Wv[d][a]), Wv is f32 ----------------
__global__ __launch_bounds__(256) void k0_transpose(
    const float* __restrict__ Wv, ushort_t* __restrict__ WvT)
{
    __shared__ ushort_t tile[32][33];
    int bx = blockIdx.x, by = blockIdx.y;
    int t = threadIdx.x, r = t >> 5, c = t & 31;
#pragma unroll
    for (int i = 0; i < 4; ++i) {
        int row = r + 8 * i;
        tile[row][c] = f2bf(Wv[(size_t)(by * 32 + row) * A_ + bx * 32 + c]);
    }
    __syncthreads();
#pragma unroll
    for (int i = 0; i < 4; ++i) {
        int row = r + 8 * i;
        WvT[(size_t)(bx * 32 + row) * D_ + by * 32 + c] = tile[c][row];
    }
}

// ---------------- K1: hidden[b][a] = dh@Wh+bh; s_att[b] (all f32) ----------------
__global__ __launch_bounds__(256) void k1_hidden_satt(
    const float* __restrict__ dh, const float* __restrict__ st,
    const float* __restrict__ Wh, const float* __restrict__ bh,
    const float* __restrict__ Ws, const float* __restrict__ bs,
    const float* __restrict__ Was, const float* __restrict__ bas,
    float* __restrict__ hidden_ws, float* __restrict__ satt_ws)
{
    __shared__ float dh_s[D_];
    __shared__ float st_s[D_];
    __shared__ float red[4];
    int b = blockIdx.x, t = threadIdx.x;
    dh_s[t]       = dh[(size_t)b * D_ + t];
    dh_s[t + 256] = dh[(size_t)b * D_ + t + 256];
    st_s[t]       = st[(size_t)b * D_ + t];
    st_s[t + 256] = st[(size_t)b * D_ + t + 256];
    __syncthreads();
    int a0 = 2 * t;
    float hh0 = 0.f, hh1 = 0.f, ss0 = 0.f, ss1 = 0.f;
#pragma unroll 4
    for (int d = 0; d < D_; ++d) {
        float2 wh  = *(const float2*)(Wh + (size_t)d * A_ + a0);
        float2 wsv = *(const float2*)(Ws + (size_t)d * A_ + a0);
        float dv = dh_s[d], sv = st_s[d];
        hh0 = fmaf(dv, wh.x,  hh0);
        hh1 = fmaf(dv, wh.y,  hh1);
        ss0 = fmaf(sv, wsv.x, ss0);
        ss1 = fmaf(sv, wsv.y, ss1);
    }
    float h0 = hh0 + bh[a0], h1 = hh1 + bh[a0 + 1];
    float s0 = ss0 + bs[a0], s1 = ss1 + bs[a0 + 1];
    hidden_ws[(size_t)b * A_ + a0]     = h0;
    hidden_ws[(size_t)b * A_ + a0 + 1] = h1;
    float part = Was[a0]     * tanh_fast(s0 + h0)
               + Was[a0 + 1] * tanh_fast(s1 + h1);
#pragma unroll
    for (int o = 32; o >= 1; o >>= 1) part += __shfl_down(part, o, 64);
    if ((t & 63) == 0) red[t >> 6] = part;
    __syncthreads();
    if (t == 0)
        satt_ws[b] = red[0] + red[1] + red[2] + red[3] + bas[0];
}

// ---------------- K2: z[b][p] = Wav . tanh(E@Wv + bv + hidden) + bav ----------------
#define TP 32
__global__ __launch_bounds__(256, 2) void k2_z(
    const float* __restrict__ E, const ushort_t* __restrict__ WvT,
    const float* __restrict__ hidden_ws, const float* __restrict__ bv,
    const float* __restrict__ Wav, const float* __restrict__ bav,
    float* __restrict__ z_ws)
{
    // 520 = 512 + 8 pad: row stride 1040 B keeps 16B alignment, breaks bank aliasing
    __shared__ ushort_t Et[TP][520] __attribute__((aligned(16)));
    __shared__ float hv_s[A_];
    __shared__ float wav_s[A_];
    __shared__ float zbuf[2][TP];

    int b  = blockIdx.y;
    int p0 = blockIdx.x * TP;
    int tid = threadIdx.x;

    // stage hidden+bv and Wav (f32)
#pragma unroll
    for (int i = 0; i < 2; ++i) {
        int a = tid + 256 * i;
        hv_s[a]  = hidden_ws[(size_t)b * A_ + a] + bv[a];
        wav_s[a] = Wav[a];
    }
    // stage E tile: 32 rows x 512 f32 -> bf16. 128 float4/row, 8 threads/row x 16 each
    {
        int r = tid >> 3, c8 = tid & 7;
        int p = p0 + r; if (p > P_ - 1) p = P_ - 1;
        const float4* src = (const float4*)(E + ((size_t)b * P_ + p) * D_);
        u64* dst = (u64*)(&Et[r][0]);
#pragma unroll
        for (int i = 0; i < 16; ++i) {
            int j = c8 + 8 * i;
            dst[j] = pack4bf(src[j]);
        }
    }
    __syncthreads();

    int lane = tid & 63;
    int w    = tid >> 6;
    int wp   = w & 1;        // which 16-row p-tile
    int wa   = w >> 1;       // which 256-wide a-half
    int col  = lane & 15;
    int q    = lane >> 4;

    f32x4 acc[16];
#pragma unroll
    for (int t = 0; t < 16; ++t) acc[t] = (f32x4){0.f, 0.f, 0.f, 0.f};

    // A-frag: A[m=col][k = q*8 + j]  (m89-verified layout)
    const ushort_t* arow  = &Et[wp * 16 + col][q * 8];
    // B-frag: B[k = q*8+j][n=col] = Wv[k][n] = WvT[n][k], k-contiguous
    const ushort_t* bbase = WvT + ((size_t)(wa * 256 + col)) * D_ + q * 8;

    for (int ks = 0; ks < 16; ++ks) {
        bf16x8 af = *(const bf16x8*)(arow + ks * 32);
#pragma unroll
        for (int t = 0; t < 16; ++t) {
            bf16x8 bfr = *(const bf16x8*)(bbase + (size_t)t * 16 * D_ + ks * 32);
            acc[t] = __builtin_amdgcn_mfma_f32_16x16x32_bf16(af, bfr, acc[t], 0, 0, 0);
        }
    }

    // epilogue: per lane holds D[m = q*4+reg][n = col] per tile t
    float zacc[4] = {0.f, 0.f, 0.f, 0.f};
#pragma unroll
    for (int t = 0; t < 16; ++t) {
        int a = wa * 256 + t * 16 + col;
        float h = hv_s[a], wv = wav_s[a];
#pragma unroll
        for (int r = 0; r < 4; ++r)
            zacc[r] += wv * tanh_fast(acc[t][r] + h);
    }
#pragma unroll
    for (int r = 0; r < 4; ++r) {
#pragma unroll
        for (int m = 1; m < 16; m <<= 1)
            zacc[r] += __shfl_xor(zacc[r], m, 64);
    }
    if (col == 0) {
#pragma unroll
        for (int r = 0; r < 4; ++r)
            zbuf[wa][wp * 16 + q * 4 + r] = zacc[r];
    }
    __syncthreads();
    if (tid < TP) {
        int p = p0 + tid;
        if (p < P_)
            z_ws[(size_t)b * P_ + p] = zbuf[0][tid] + zbuf[1][tid] + bav[0];
    }
}

// ---------------- K3: softmax(z) -> alpha; extended softmax -> beta ----------------
__global__ __launch_bounds__(256) void k3_softmax(
    const float* __restrict__ z_ws, const float* __restrict__ satt_ws,
    float* __restrict__ alpha_ws, float* __restrict__ beta_ws,
    float* __restrict__ out)
{
    __shared__ float red[4];
    __shared__ float bm, bl;
    int b = blockIdx.x, t = threadIdx.x;
    float zv = (t < P_) ? z_ws[(size_t)b * P_ + t] : -1e30f;

    float m = zv;
#pragma unroll
    for (int o = 32; o >= 1; o >>= 1) m = fmaxf(m, __shfl_xor(m, o, 64));
    if ((t & 63) == 0) red[t >> 6] = m;
    __syncthreads();
    if (t == 0) bm = fmaxf(fmaxf(red[0], red[1]), fmaxf(red[2], red[3]));
    __syncthreads();
    float m1 = bm;

    float e = (t < P_) ? __expf(zv - m1) : 0.f;
    float s = e;
#pragma unroll
    for (int o = 32; o >= 1; o >>= 1) s += __shfl_xor(s, o, 64);
    if ((t & 63) == 0) red[t >> 6] = s;
    __syncthreads();
    if (t == 0) bl = red[0] + red[1] + red[2] + red[3];
    __syncthreads();
    float l1 = bl;

    if (t < P_) {
        float alpha = e / l1;
        alpha_ws[(size_t)b * P_ + t] = alpha;
        out[OUT_ALPHA + (size_t)b * P_ + t] = alpha;
    }
    float sa = satt_ws[b];
    float m2 = fmaxf(m1, sa);
    float l2 = __expf(m1 - m2) * l1 + __expf(sa - m2);
    float beta = __expf(sa - m2) / l2;
    if (t == 0) {
        beta_ws[b] = beta;
        out[OUT_BETA + b] = beta;
    }
}

// ---------------- K4: c_t = E^T alpha; c_hat = beta*st + (1-beta)*c_t ----------------
__global__ __launch_bounds__(256) void k4_ct(
    const float* __restrict__ E, const float* __restrict__ st,
    const float* __restrict__ alpha_ws, const float* __restrict__ beta_ws,
    float* __restrict__ out)
{
    __shared__ float al[P_];
    int b = blockIdx.x, t = threadIdx.x;
    if (t < P_) al[t] = alpha_ws[(size_t)b * P_ + t];
    __syncthreads();
    const float* eb = E + (size_t)b * P_ * D_ + 2 * t;
    float a0 = 0.f, a1 = 0.f;
#pragma unroll 4
    for (int p = 0; p < P_; ++p) {
        float2 u = *(const float2*)(eb + (size_t)p * D_);
        float ap = al[p];
        a0 = fmaf(ap, u.x, a0);
        a1 = fmaf(ap, u.y, a1);
    }
    float beta = beta_ws[b];
    float2 su = *(const float2*)(st + (size_t)b * D_ + 2 * t);
    float c0 = beta * su.x + (1.f - beta) * a0;
    float c1 = beta * su.y + (1.f - beta) * a1;
    *(float2*)(out + (size_t)b * D_ + 2 * t) = make_float2(c0, c1);
}

extern "C" void kernel_launch(void* const* d_in, const int* in_sizes, int n_in,
                              void* d_out, int out_size, void* d_ws, size_t ws_size,
                              hipStream_t stream)
{
    (void)in_sizes; (void)n_in; (void)out_size; (void)ws_size;
    const float* E   = (const float*)d_in[0];
    const float* dh  = (const float*)d_in[1];
    const float* st  = (const float*)d_in[2];
    const float* Wv  = (const float*)d_in[3];
    const float* bv  = (const float*)d_in[4];
    const float* Wh  = (const float*)d_in[5];
    const float* bh  = (const float*)d_in[6];
    const float* Ws  = (const float*)d_in[7];
    const float* bs  = (const float*)d_in[8];
    const float* Wav = (const float*)d_in[9];
    const float* bav = (const float*)d_in[10];
    const float* Was = (const float*)d_in[11];
    const float* bas = (const float*)d_in[12];
    float* out = (float*)d_out;

    char* ws = (char*)d_ws;
    ushort_t* WvT      = (ushort_t*)(ws);            // 524288 B (bf16 A x D)
    float*    hidden_w = (float*)(ws + 524288);      // 524288 B
    float*    satt_w   = (float*)(ws + 1048576);     // 1024 B
    float*    z_w      = (float*)(ws + 1049600);     // 200704 B
    float*    alpha_w  = (float*)(ws + 1250304);     // 200704 B
    float*    beta_w   = (float*)(ws + 1451008);     // 1024 B  (total ~1.42 MB)

    k0_transpose<<<dim3(16, 16), 256, 0, stream>>>(Wv, WvT);
    k1_hidden_satt<<<256, 256, 0, stream>>>(dh, st, Wh, bh, Ws, bs, Was, bas,
                                            hidden_w, satt_w);
    k2_z<<<dim3(7, 256), 256, 0, stream>>>(E, WvT, hidden_w, bv, Wav, bav, z_w);
    k3_softmax<<<256, 256, 0, stream>>>(z_w, satt_w, alpha_w, beta_w, out);
    k4_ct<<<256, 256, 0, stream>>>(E, st, alpha_w, beta_w, out);
}

// Round 4
// 323.748 us; speedup vs baseline: 1.5786x; 1.5786x over previous
//
#include <hip/hip_runtime.h>
#include <hip/hip_bf16.h>
#include <cstdint>

#define B_ 256
#define P_ 196
#define D_ 512
#define A_ 512

#define OUT_CHAT  0
#define OUT_ALPHA (B_*D_)            // 131072
#define OUT_BETA  (B_*D_ + B_*P_)    // 181248

typedef unsigned short ushort_t;
typedef uint32_t u32;
typedef uint64_t u64;
typedef __attribute__((ext_vector_type(8))) __bf16 bf16x8;
typedef __attribute__((ext_vector_type(4))) float f32x4;

__device__ __forceinline__ ushort_t f2bf(float f) {
    union { float f; u32 i; } v; v.f = f;
    u32 r = (v.i + 0x7fffu + ((v.i >> 16) & 1u)) >> 16;
    return (ushort_t)r;
}
__device__ __forceinline__ u64 pack4bf(float4 v) {
    return (u64)f2bf(v.x) | ((u64)f2bf(v.y) << 16)
         | ((u64)f2bf(v.z) << 32) | ((u64)f2bf(v.w) << 48);
}
// tanh(x) = 1 - 2/(1+e^{2x}); exact at +-inf limits, ~1e-6 abs err
__device__ __forceinline__ float tanh_fast(float x) {
    float e = __expf(2.0f * x);
    return 1.0f - 2.0f / (e + 1.0f);
}

// ---------------- K0: WvT[a][d] = bf16(Wv[d][a]), Wv is f32 ----------------
__global__ __launch_bounds__(256) void k0_transpose(
    const float* __restrict__ Wv, ushort_t* __restrict__ WvT)
{
    __shared__ ushort_t tile[32][33];
    int bx = blockIdx.x, by = blockIdx.y;
    int t = threadIdx.x, r = t >> 5, c = t & 31;
#pragma unroll
    for (int i = 0; i < 4; ++i) {
        int row = r + 8 * i;
        tile[row][c] = f2bf(Wv[(size_t)(by * 32 + row) * A_ + bx * 32 + c]);
    }
    __syncthreads();
#pragma unroll
    for (int i = 0; i < 4; ++i) {
        int row = r + 8 * i;
        WvT[(size_t)(bx * 32 + row) * D_ + by * 32 + c] = tile[c][row];
    }
}

// ------- K1: hidden[b][a] = dh@Wh+bh; s_att[b]; zero z_ws & ct_ws -------
__global__ __launch_bounds__(256) void k1_hidden_satt(
    const float* __restrict__ dh, const float* __restrict__ st,
    const float* __restrict__ Wh, const float* __restrict__ bh,
    const float* __restrict__ Ws, const float* __restrict__ bs,
    const float* __restrict__ Was, const float* __restrict__ bas,
    float* __restrict__ hidden_ws, float* __restrict__ satt_ws,
    float* __restrict__ z_ws, float* __restrict__ ct_ws)
{
    __shared__ float dh_s[D_];
    __shared__ float st_s[D_];
    __shared__ float red[4];
    int b = blockIdx.x, t = threadIdx.x;
    // zero accumulation buffers for this batch row
    if (t < P_) z_ws[(size_t)b * P_ + t] = 0.f;
    ct_ws[(size_t)b * D_ + t]       = 0.f;
    ct_ws[(size_t)b * D_ + t + 256] = 0.f;

    dh_s[t]       = dh[(size_t)b * D_ + t];
    dh_s[t + 256] = dh[(size_t)b * D_ + t + 256];
    st_s[t]       = st[(size_t)b * D_ + t];
    st_s[t + 256] = st[(size_t)b * D_ + t + 256];
    __syncthreads();
    int a0 = 2 * t;
    float hh0 = 0.f, hh1 = 0.f, ss0 = 0.f, ss1 = 0.f;
#pragma unroll 4
    for (int d = 0; d < D_; ++d) {
        float2 wh  = *(const float2*)(Wh + (size_t)d * A_ + a0);
        float2 wsv = *(const float2*)(Ws + (size_t)d * A_ + a0);
        float dv = dh_s[d], sv = st_s[d];
        hh0 = fmaf(dv, wh.x,  hh0);
        hh1 = fmaf(dv, wh.y,  hh1);
        ss0 = fmaf(sv, wsv.x, ss0);
        ss1 = fmaf(sv, wsv.y, ss1);
    }
    float h0 = hh0 + bh[a0], h1 = hh1 + bh[a0 + 1];
    float s0 = ss0 + bs[a0], s1 = ss1 + bs[a0 + 1];
    hidden_ws[(size_t)b * A_ + a0]     = h0;
    hidden_ws[(size_t)b * A_ + a0 + 1] = h1;
    float part = Was[a0]     * tanh_fast(s0 + h0)
               + Was[a0 + 1] * tanh_fast(s1 + h1);
#pragma unroll
    for (int o = 32; o >= 1; o >>= 1) part += __shfl_down(part, o, 64);
    if ((t & 63) == 0) red[t >> 6] = part;
    __syncthreads();
    if (t == 0)
        satt_ws[b] = red[0] + red[1] + red[2] + red[3] + bas[0];
}

// ---- K2: z[b][p] += Wav . tanh(E@Wv + bv + hidden)  (m93-style LDS GEMM) ----
// GEMM view: M = B*P = 50176 (=392*128), N = 512, K = 512.
// BM=128, BN=256, BK=64; 4 waves, each owns 64 rows x 128 cols (4x8 MFMA tiles).
#define BM 128
#define BN 256
#define BKk 64
#define PADK 72   // LDS row pitch (bf16): 144 B, 16B-aligned, breaks pow2 banks
__global__ __launch_bounds__(256, 2) void k2_z(
    const float* __restrict__ E, const ushort_t* __restrict__ WvT,
    const float* __restrict__ hidden_ws, const float* __restrict__ bv,
    const float* __restrict__ Wav, float* __restrict__ z_ws)
{
    __shared__ ushort_t As[BM * PADK];   // [m][k]
    __shared__ ushort_t Bs[BN * PADK];   // [n][k]
    __shared__ float hv_s[2][BN];
    __shared__ float wav_s[BN];
    __shared__ float zpart[2][BM];

    int tid = threadIdx.x;
    int m0  = blockIdx.x * BM;
    int n0  = blockIdx.y * BN;
    int b0  = m0 / P_;
    int b1  = (m0 + BM - 1) / P_;   // at most b0+1 since BM < P_

    {   // stage hidden+bv (both possible b's) and Wav for this n-chunk
        int a = n0 + tid;
        float bva = bv[a];
        hv_s[0][tid] = hidden_ws[(size_t)b0 * A_ + a] + bva;
        hv_s[1][tid] = hidden_ws[(size_t)b1 * A_ + a] + bva;
        wav_s[tid]   = Wav[a];
    }

    int lane = tid & 63, w = tid >> 6;
    int wm = w & 1, wn = w >> 1;
    int col = lane & 15, q = lane >> 4;

    f32x4 acc[4][8];
#pragma unroll
    for (int tm = 0; tm < 4; ++tm)
#pragma unroll
        for (int tn = 0; tn < 8; ++tn)
            acc[tm][tn] = (f32x4){0.f, 0.f, 0.f, 0.f};

    const ushort_t* arow = As + (wm * 64 + col) * PADK + q * 8;
    const ushort_t* brow = Bs + (wn * 128 + col) * PADK + q * 8;

    for (int kt = 0; kt < D_ / BKk; ++kt) {
        {   // stage A: 128 rows x 64 f32 -> bf16; 2 threads/row, 32 floats each
            int r = tid >> 1, half = tid & 1;
            const float4* src = (const float4*)(E + ((size_t)(m0 + r)) * D_ + kt * BKk + half * 32);
            u64* dst = (u64*)(As + r * PADK + half * 32);
#pragma unroll
            for (int i = 0; i < 8; ++i) dst[i] = pack4bf(src[i]);
        }
        {   // stage B: 256 rows x 64 bf16; 1 thread/row, 128 B each
            const uint4* src = (const uint4*)(WvT + ((size_t)(n0 + tid)) * D_ + kt * BKk);
            uint4* dst = (uint4*)(Bs + tid * PADK);
#pragma unroll
            for (int i = 0; i < 8; ++i) dst[i] = src[i];
        }
        __syncthreads();
#pragma unroll
        for (int ks = 0; ks < 2; ++ks) {
            bf16x8 afr[4], bfr[8];
#pragma unroll
            for (int tm = 0; tm < 4; ++tm)
                afr[tm] = *(const bf16x8*)(arow + tm * 16 * PADK + ks * 32);
#pragma unroll
            for (int tn = 0; tn < 8; ++tn)
                bfr[tn] = *(const bf16x8*)(brow + tn * 16 * PADK + ks * 32);
#pragma unroll
            for (int tm = 0; tm < 4; ++tm)
#pragma unroll
                for (int tn = 0; tn < 8; ++tn)
                    acc[tm][tn] = __builtin_amdgcn_mfma_f32_16x16x32_bf16(
                        afr[tm], bfr[tn], acc[tm][tn], 0, 0, 0);
        }
        __syncthreads();
    }

    // epilogue: z-partial per row over this 256-col chunk
#pragma unroll
    for (int tm = 0; tm < 4; ++tm) {
#pragma unroll
        for (int r = 0; r < 4; ++r) {
            int row = wm * 64 + tm * 16 + q * 4 + r;
            int m   = m0 + row;
            int bsel = (m / P_) - b0;
            float zr = 0.f;
#pragma unroll
            for (int tn = 0; tn < 8; ++tn) {
                int nl = wn * 128 + tn * 16 + col;
                zr += wav_s[nl] * tanh_fast(acc[tm][tn][r] + hv_s[bsel][nl]);
            }
#pragma unroll
            for (int msk = 1; msk < 16; msk <<= 1)
                zr += __shfl_xor(zr, msk, 64);
            if (col == 0) zpart[wn][row] = zr;
        }
    }
    __syncthreads();
    if (tid < BM) {
        int m = m0 + tid;
        int b = m / P_;
        int p = m - b * P_;
        atomicAdd(&z_ws[(size_t)b * P_ + p], zpart[0][tid] + zpart[1][tid]);
    }
}

// ---------------- K3: softmax(z+bav) -> alpha; extended softmax -> beta ----------------
__global__ __launch_bounds__(256) void k3_softmax(
    const float* __restrict__ z_ws, const float* __restrict__ satt_ws,
    const float* __restrict__ bav,
    float* __restrict__ alpha_ws, float* __restrict__ beta_ws,
    float* __restrict__ out)
{
    __shared__ float red[4];
    __shared__ float bm_s, bl_s;
    int b = blockIdx.x, t = threadIdx.x;
    float zv = (t < P_) ? (z_ws[(size_t)b * P_ + t] + bav[0]) : -1e30f;

    float m = zv;
#pragma unroll
    for (int o = 32; o >= 1; o >>= 1) m = fmaxf(m, __shfl_xor(m, o, 64));
    if ((t & 63) == 0) red[t >> 6] = m;
    __syncthreads();
    if (t == 0) bm_s = fmaxf(fmaxf(red[0], red[1]), fmaxf(red[2], red[3]));
    __syncthreads();
    float m1 = bm_s;

    float e = (t < P_) ? __expf(zv - m1) : 0.f;
    float s = e;
#pragma unroll
    for (int o = 32; o >= 1; o >>= 1) s += __shfl_xor(s, o, 64);
    if ((t & 63) == 0) red[t >> 6] = s;
    __syncthreads();
    if (t == 0) bl_s = red[0] + red[1] + red[2] + red[3];
    __syncthreads();
    float l1 = bl_s;

    if (t < P_) {
        float alpha = e / l1;
        alpha_ws[(size_t)b * P_ + t] = alpha;
        out[OUT_ALPHA + (size_t)b * P_ + t] = alpha;
    }
    float sa = satt_ws[b];
    float m2 = fmaxf(m1, sa);
    float l2 = __expf(m1 - m2) * l1 + __expf(sa - m2);
    float beta = __expf(sa - m2) / l2;
    if (t == 0) {
        beta_ws[b] = beta;
        out[OUT_BETA + b] = beta;
    }
}

// ---------------- K4a: ct_ws[b][:] += E[b,pc-chunk]^T alpha ----------------
#define PCH 49
__global__ __launch_bounds__(256) void k4_ct_partial(
    const float* __restrict__ E, const float* __restrict__ alpha_ws,
    float* __restrict__ ct_ws)
{
    __shared__ float al[PCH];
    int b = blockIdx.x, pc = blockIdx.y, t = threadIdx.x;
    int pbase = pc * PCH;
    if (t < PCH) al[t] = alpha_ws[(size_t)b * P_ + pbase + t];
    __syncthreads();
    const float* eb = E + ((size_t)b * P_ + pbase) * D_ + 2 * t;
    float a0 = 0.f, a1 = 0.f;
#pragma unroll 7
    for (int p = 0; p < PCH; ++p) {
        float2 u = *(const float2*)(eb + (size_t)p * D_);
        float ap = al[p];
        a0 = fmaf(ap, u.x, a0);
        a1 = fmaf(ap, u.y, a1);
    }
    atomicAdd(&ct_ws[(size_t)b * D_ + 2 * t],     a0);
    atomicAdd(&ct_ws[(size_t)b * D_ + 2 * t + 1], a1);
}

// ---------------- K4b: c_hat = beta*st + (1-beta)*c_t ----------------
__global__ __launch_bounds__(256) void k4_combine(
    const float* __restrict__ st, const float* __restrict__ ct_ws,
    const float* __restrict__ beta_ws, float* __restrict__ out)
{
    int b = blockIdx.x, t = threadIdx.x;
    float beta = beta_ws[b];
    float2 su = *(const float2*)(st + (size_t)b * D_ + 2 * t);
    float2 cu = *(const float2*)(ct_ws + (size_t)b * D_ + 2 * t);
    float c0 = beta * su.x + (1.f - beta) * cu.x;
    float c1 = beta * su.y + (1.f - beta) * cu.y;
    *(float2*)(out + (size_t)b * D_ + 2 * t) = make_float2(c0, c1);
}

extern "C" void kernel_launch(void* const* d_in, const int* in_sizes, int n_in,
                              void* d_out, int out_size, void* d_ws, size_t ws_size,
                              hipStream_t stream)
{
    (void)in_sizes; (void)n_in; (void)out_size; (void)ws_size;
    const float* E   = (const float*)d_in[0];
    const float* dh  = (const float*)d_in[1];
    const float* st  = (const float*)d_in[2];
    const float* Wv  = (const float*)d_in[3];
    const float* bv  = (const float*)d_in[4];
    const float* Wh  = (const float*)d_in[5];
    const float* bh  = (const float*)d_in[6];
    const float* Ws  = (const float*)d_in[7];
    const float* bs  = (const float*)d_in[8];
    const float* Wav = (const float*)d_in[9];
    const float* bav = (const float*)d_in[10];
    const float* Was = (const float*)d_in[11];
    const float* bas = (const float*)d_in[12];
    float* out = (float*)d_out;

    char* ws = (char*)d_ws;
    ushort_t* WvT      = (ushort_t*)(ws);            // 524288 B (bf16 A x D)
    float*    hidden_w = (float*)(ws + 524288);      // 524288 B
    float*    satt_w   = (float*)(ws + 1048576);     // 1024 B
    float*    z_w      = (float*)(ws + 1049600);     // 200704 B
    float*    alpha_w  = (float*)(ws + 1250304);     // 200704 B
    float*    beta_w   = (float*)(ws + 1451008);     // 1024 B
    float*    ct_w     = (float*)(ws + 1452032);     // 524288 B (total ~1.98 MB)

    k0_transpose<<<dim3(16, 16), 256, 0, stream>>>(Wv, WvT);
    k1_hidden_satt<<<256, 256, 0, stream>>>(dh, st, Wh, bh, Ws, bs, Was, bas,
                                            hidden_w, satt_w, z_w, ct_w);
    k2_z<<<dim3((B_ * P_) / BM, A_ / BN), 256, 0, stream>>>(E, WvT, hidden_w, bv,
                                                            Wav, z_w);
    k3_softmax<<<256, 256, 0, stream>>>(z_w, satt_w, bav, alpha_w, beta_w, out);
    k4_ct_partial<<<dim3(B_, P_ / PCH), 256, 0, stream>>>(E, alpha_w, ct_w);
    k4_combine<<<256, 256, 0, stream>>>(st, ct_w, beta_w, out);
}